// Round 11
// baseline (171.851 us; speedup 1.0000x reference)
//
#include <hip/hip_runtime.h>
#include <math.h>

#define Bb 16
#define Nn 1024
#define Dd 16
#define NL 15

typedef __attribute__((ext_vector_type(8))) short short8;
typedef __attribute__((ext_vector_type(16))) float f32x16;
typedef __attribute__((ext_vector_type(4))) unsigned uint4v;

#if __has_builtin(__builtin_amdgcn_exp2f)
#define EXP2(x) __builtin_amdgcn_exp2f(x)
#else
#define EXP2(x) exp2f(x)
#endif

// LDS layout (dynamic, 68224 B -> 2 blocks/CU = 136448 <= 160K):
//   K    : [1024 keys][16 shorts]          offset 0      32768 B
//   V^T  : [16 d][VSTR=1044 shorts]        offset 32768  33408 B (522-dw row
//          stride, d*10 mod 32 all distinct -> conflict-free)
//   ones : [1024 shorts] bf16(1.0)         offset 66176   2048 B
//   O    : 16 waves x [32 q][17 f32]       offset 0      34816 B (overlays
//          K (+2KB of V) after the loop barrier)
//   rs   : 16 waves x [32 f32]             offset 36864   2048 B (in dead V)
#define VSTR 1044
#define V_OFF 32768
#define ONES_OFF 66176
#define RS_OFF 36864
#define LDS_TOTAL 68224

// round-half-up fp32->bf16 (proj staging)
__device__ __forceinline__ unsigned pack2bf(float a, float b) {
    unsigned ua = __float_as_uint(a) + 0x8000u;
    unsigned ub = __float_as_uint(b) + 0x8000u;
    return (ua >> 16) | (ub & 0xffff0000u);
}
__device__ __forceinline__ unsigned short bf1(float a) {
    return (unsigned short)((__float_as_uint(a) + 0x8000u) >> 16);
}

// exp2 both, truncate-pack to bf16 pair in ONE v_perm_b32
__device__ __forceinline__ unsigned expperm(float x, float y) {
    unsigned ex = __float_as_uint(EXP2(x));
    unsigned ey = __float_as_uint(EXP2(y));
#if __has_builtin(__builtin_amdgcn_perm)
    return __builtin_amdgcn_perm(ey, ex, 0x07060302);   // {ey.hi16, ex.hi16}
#else
    return (ex >> 16) | (ey & 0xffff0000u);
#endif
}

__device__ __forceinline__ void project(const float* __restrict__ xrow,
                                        const float* __restrict__ W,
                                        const float* __restrict__ bias,
                                        int i, float* __restrict__ q) {
#pragma unroll
    for (int r = 0; r < 16; r++) q[r] = 0.f;
    for (int c = 0; c < i; c++) {
        float xc = xrow[c];
#pragma unroll
        for (int r = 0; r < 16; r++) q[r] = fmaf(xc, W[r * 16 + c], q[r]);
    }
#pragma unroll
    for (int r = 0; r < 16; r++) q[r] = (r < i) ? (q[r] + bias[r]) : 0.f;
}

__device__ __forceinline__ void load_row16(const float* __restrict__ p, float* __restrict__ x) {
    const float4* xp = (const float4*)p;
    float4 a = xp[0], b = xp[1], c = xp[2], d = xp[3];
    x[0]=a.x; x[1]=a.y; x[2]=a.z; x[3]=a.w;
    x[4]=b.x; x[5]=b.y; x[6]=b.z; x[7]=b.w;
    x[8]=c.x; x[9]=c.y; x[10]=c.z; x[11]=c.w;
    x[12]=d.x; x[13]=d.y; x[14]=d.z; x[15]=d.w;
}

// two b64 LDS reads -> one B-frag (keys {base+4h+0..3, base+8+4h+0..3})
__device__ __forceinline__ short8 ldv(const unsigned short* __restrict__ p) {
    uint2 a = *(const uint2*)p;
    uint2 b = *(const uint2*)(p + 8);
    uint4v v = {a.x, a.y, b.x, b.y};
    return __builtin_bit_cast(short8, v);
}

// ---------------------------------------------------------------------------
// Layer 0: Z col 0 + logdet = -alpha0 (atomicAdd target for the layers)
// ---------------------------------------------------------------------------
__global__ void gf_init(const float* __restrict__ X, const float* __restrict__ ip,
                        float* __restrict__ out) {
    int idx = blockIdx.x * blockDim.x + threadIdx.x;
    if (idx >= Bb * Nn) return;
    float mu = ip[0], alpha = ip[1];
    float x0 = X[(size_t)idx * Dd];
    out[(size_t)idx * Dd] = (x0 - mu) * __expf(-alpha);
    out[(size_t)Bb * Nn * Dd + idx] = -alpha;
}

// ---------------------------------------------------------------------------
// Fused flash attention, single 32-query stream per wave, grid (NL, Bb, 2).
// Block z covers queries z*512..; wave wid covers z*512 + wid*32 .. +31.
// Each block stages all 1024 K/V rows. rs via ones-column (PV col 16);
// P pack via v_perm trunc. launch_bounds (1024,4): natural VGPR (~50) is
// already <=64, so HW co-schedules 2 blocks/CU (LDS 2x68224 fits) WITHOUT
// forcing the allocator (R10's (1024,8) forced VGPR=32 -> 55MB scratch).
// ---------------------------------------------------------------------------
__launch_bounds__(1024, 4)
__global__ void gf_fused(const float* __restrict__ X,
                         const float* __restrict__ Wq, const float* __restrict__ bq,
                         const float* __restrict__ Wk, const float* __restrict__ bk,
                         const float* __restrict__ Wv, const float* __restrict__ bv,
                         const float* __restrict__ Wo, const float* __restrict__ bo,
                         const float* __restrict__ Wf, const float* __restrict__ bf,
                         float* __restrict__ out) {
    extern __shared__ char smem[];
    const int l = blockIdx.x, b = blockIdx.y, z = blockIdx.z, i = l + 1;
    const int t = threadIdx.x;
    const int wid = t >> 6, lane = t & 63;
    const int q31 = lane & 31, h = lane >> 5;
    const int qbase = z * 512 + wid * 32;            // wave's 32 queries
    const float qscale = 1.4426950408889634f * rsqrtf((float)i);

    unsigned short* Ksh  = (unsigned short*)smem;
    unsigned short* Vsh  = (unsigned short*)(smem + V_OFF);
    unsigned short* Ones = (unsigned short*)(smem + ONES_OFF);

    const float* Xb  = X  + (size_t)b * Nn * Dd;
    const float* wq  = Wq + l * 256;  const float* bql = bq + l * 16;
    const float* wk  = Wk + l * 256;  const float* bkl = bk + l * 16;
    const float* wvp = Wv + l * 256;  const float* bvl = bv + l * 16;
    const float* wo  = Wo + l * 256;  const float* bol = bo + l * 16;
    const float* wf  = Wf + l * 32;   const float* bfl = bf + l * 2;

    // ---- proj phase: thread t stages K/V row t; Q for its wave's query ----
    unsigned qu[8];                  // Q row (qbase + q31), scaled, bf16 pairs
    {
        float xr[16]; load_row16(Xb + (size_t)t * Dd, xr);
        float tmp[16];
        unsigned u[8];

        project(xr, wk, bkl, i, tmp);
#pragma unroll
        for (int r = 0; r < 8; r++) u[r] = pack2bf(tmp[2*r], tmp[2*r+1]);
        {
            uint4* kd = (uint4*)(Ksh + t * 16);
            kd[0] = make_uint4(u[0], u[1], u[2], u[3]);
            kd[1] = make_uint4(u[4], u[5], u[6], u[7]);
        }

        project(xr, wvp, bvl, i, tmp);
#pragma unroll
        for (int d = 0; d < 16; d++) Vsh[d * VSTR + t] = bf1(tmp[d]);

        Ones[t] = 0x3F80;            // bf16(1.0)

        float xq[16]; load_row16(Xb + (size_t)(qbase + q31) * Dd, xq);
        project(xq, wq, bql, i, tmp);
#pragma unroll
        for (int r = 0; r < 8; r++) qu[r] = pack2bf(tmp[2*r] * qscale, tmp[2*r+1] * qscale);
    }
    __syncthreads();

    // ---- Q B-frag via same-wave shuffles: B[col=q31][k=8h+j] ----
    short8 qf;
    {
        unsigned d0[4];
#pragma unroll
        for (int j = 0; j < 4; j++) {
            unsigned lo = __shfl(qu[j], q31);
            unsigned hi = __shfl(qu[4 + j], q31);
            d0[j] = h ? hi : lo;
        }
        uint4v v0 = {d0[0], d0[1], d0[2], d0[3]};
        qf = __builtin_bit_cast(short8, v0);
    }

    // ---------------- attention loop (32 keys/iter) ----------------
    f32x16 zf16 = {};
    f32x16 D0 = {};

    const unsigned short* Kp = Ksh + (size_t)q31 * 16 + h * 8;   // A: K[key][8h+j]
    // lanes q31<16: V^T row d=q31; lanes q31>=16: ones row (rs column 16)
    const unsigned short* Vp = ((q31 < 16) ? (Vsh + (size_t)q31 * VSTR) : Ones) + 4 * h;

    short8 kf = *(const short8*)Kp;

    for (int kb = 0; kb < Nn; kb += 32) {
        const int kn = (kb + 32) & (Nn - 1);
        short8 vc0 = ldv(Vp + kb);
        short8 vc1 = ldv(Vp + kb + 16);

        f32x16 s0 = __builtin_amdgcn_mfma_f32_32x32x16_bf16(kf, qf, zf16, 0, 0, 0);
        kf = *(const short8*)(Kp + (size_t)kn * 16);   // prefetch next K frag

        // sub-chunk 0: S regs 0..7 (keys kb+{4h+0..3, 8+4h+0..3})
        {
            uint4v a0 = {expperm(s0[0], s0[1]), expperm(s0[2], s0[3]),
                         expperm(s0[4], s0[5]), expperm(s0[6], s0[7])};
            D0 = __builtin_amdgcn_mfma_f32_32x32x16_bf16(
                     __builtin_bit_cast(short8, a0), vc0, D0, 0, 0, 0);
        }
        // sub-chunk 1: S regs 8..15 (keys kb+16+{4h+0..3, 8+4h+0..3})
        {
            uint4v a1 = {expperm(s0[8], s0[9]),  expperm(s0[10], s0[11]),
                         expperm(s0[12], s0[13]), expperm(s0[14], s0[15])};
            D0 = __builtin_amdgcn_mfma_f32_32x32x16_bf16(
                     __builtin_bit_cast(short8, a1), vc1, D0, 0, 0, 0);
        }
    }

    __syncthreads();   // all waves done with K/V before O overlays them

    // ---- stage O (C-layout -> [q_local][d] stride 17) + rs; wave-local ----
    float* Ow = (float*)smem + wid * (32 * 17);
    if (q31 < 16) {
#pragma unroll
        for (int r = 0; r < 16; r++) {
            int m = (r & 3) + 8 * (r >> 2) + 4 * h;   // query within wave's 32
            Ow[m * 17 + q31] = D0[r];
        }
    }
    float* Rw = (float*)(smem + RS_OFF) + wid * 32;
    if (q31 == 16) {                 // col 16 of D = sum of P = rs
#pragma unroll
        for (int r = 0; r < 16; r++) {
            int m = (r & 3) + 8 * (r >> 2) + 4 * h;
            Rw[m] = D0[r];
        }
    }
    // same-wave LDS ops are in program order; epilogue reads own-wave data.

    // ---- epilogue: lanes 0..31 handle query qbase+lane ----
    if (lane < 32) {
        const int n = qbase + lane;
        float xr[16]; load_row16(Xb + (size_t)n * Dd, xr);
        float q[16];  project(xr, wq, bql, i, q);
        const float* orow = (const float*)smem + wid * (32 * 17) + lane * 17;
        const float  inv  = 1.f / Rw[lane];

        float a[16];
#pragma unroll
        for (int c = 0; c < 16; c++) a[c] = q[c] + orow[c] * inv;

        float tt[16];
#pragma unroll
        for (int r = 0; r < 16; r++) {
            float acc = bol[r];
#pragma unroll
            for (int c = 0; c < 16; c++) acc = fmaf(a[c], wo[r * 16 + c], acc);
            tt[r] = fmaxf(acc, 0.f);
        }
#pragma unroll
        for (int r = 0; r < 16; r++) a[r] += (r < i) ? tt[r] : 0.f;

        float mu = bfl[0], al = bfl[1];
#pragma unroll
        for (int c = 0; c < 16; c++) {
            mu = fmaf(a[c], wf[c], mu);
            al = fmaf(a[c], wf[16 + c], al);
        }
        out[((size_t)(b * Nn + n)) * Dd + i] = (xr[i] - mu) * __expf(-al);
        atomicAdd(out + (size_t)Bb * Nn * Dd + b * Nn + n, -al);
    }
}

// ---------------------------------------------------------------------------
// Fallback path (R1): fp32 kernel, if big dynamic LDS unavailable
// ---------------------------------------------------------------------------
__launch_bounds__(512, 2)
__global__ void gf_layer_fb(const float* __restrict__ X,
                            const float* __restrict__ Wq, const float* __restrict__ bq,
                            const float* __restrict__ Wk, const float* __restrict__ bk,
                            const float* __restrict__ Wv, const float* __restrict__ bv,
                            const float* __restrict__ Wo, const float* __restrict__ bo,
                            const float* __restrict__ Wf, const float* __restrict__ bf,
                            float* __restrict__ out) {
    const int l = blockIdx.x, b = blockIdx.y, i = l + 1, t = threadIdx.x;
    const float rscale = rsqrtf((float)i);
    __shared__ float Ksh[512 * 16];
    __shared__ float Vsh[512 * 16];
    const float* Xb = X + (size_t)b * Nn * Dd;
    const float* wq = Wq + l * 256; const float* wk = Wk + l * 256;
    const float* wv = Wv + l * 256; const float* wo = Wo + l * 256;
    const float* wf = Wf + l * 32;
    const float* bql = bq + l * 16; const float* bkl = bk + l * 16;
    const float* bvl = bv + l * 16; const float* bol = bo + l * 16;
    const float* bfl = bf + l * 2;
    const int n0 = t, n1 = t + 512;
    float q0[16], q1[16], xi0, xi1;
    {
        float xr[16];
        load_row16(Xb + (size_t)n0 * Dd, xr); xi0 = xr[i]; project(xr, wq, bql, i, q0);
        load_row16(Xb + (size_t)n1 * Dd, xr); xi1 = xr[i]; project(xr, wq, bql, i, q1);
    }
    float o0[16], o1[16];
#pragma unroll
    for (int c = 0; c < 16; c++) { o0[c] = 0.f; o1[c] = 0.f; }
    float ls0 = 0.f, ls1 = 0.f;
    for (int ch = 0; ch < 2; ch++) {
        float kr[16], vr[16];
        {
            float kx[16];
            load_row16(Xb + (size_t)(ch * 512 + t) * Dd, kx);
            project(kx, wk, bkl, i, kr);
            project(kx, wv, bvl, i, vr);
        }
        __syncthreads();
#pragma unroll
        for (int j = 0; j < 4; j++) {
            ((float4*)&Ksh[t * 16])[j] = ((float4*)kr)[j];
            ((float4*)&Vsh[t * 16])[j] = ((float4*)vr)[j];
        }
        __syncthreads();
        for (int k = 0; k < 512; k++) {
            float kk[16], vv[16];
#pragma unroll
            for (int j = 0; j < 4; j++) ((float4*)kk)[j] = ((const float4*)&Ksh[k * 16])[j];
            float s0 = 0.f, s1 = 0.f;
#pragma unroll
            for (int c = 0; c < 16; c++) { s0 = fmaf(q0[c], kk[c], s0); s1 = fmaf(q1[c], kk[c], s1); }
            float p0 = __expf(s0 * rscale), p1 = __expf(s1 * rscale);
            ls0 += p0; ls1 += p1;
#pragma unroll
            for (int j = 0; j < 4; j++) ((float4*)vv)[j] = ((const float4*)&Vsh[k * 16])[j];
#pragma unroll
            for (int c = 0; c < 16; c++) { o0[c] = fmaf(p0, vv[c], o0[c]); o1[c] = fmaf(p1, vv[c], o1[c]); }
        }
        __syncthreads();
    }
    float* logdet = out + (size_t)Bb * Nn * Dd;
#pragma unroll
    for (int rowsel = 0; rowsel < 2; rowsel++) {
        const float* qr = rowsel ? q1 : q0; const float* orr = rowsel ? o1 : o0;
        float lsum = rowsel ? ls1 : ls0; float xin = rowsel ? xi1 : xi0;
        int n = rowsel ? n1 : n0;
        float a[16]; float inv = 1.f / lsum;
#pragma unroll
        for (int c = 0; c < 16; c++) a[c] = qr[c] + orr[c] * inv;
        float tt[16];
#pragma unroll
        for (int r = 0; r < 16; r++) {
            float acc = bol[r];
#pragma unroll
            for (int c = 0; c < 16; c++) acc = fmaf(a[c], wo[r * 16 + c], acc);
            tt[r] = fmaxf(acc, 0.f);
        }
#pragma unroll
        for (int r = 0; r < 16; r++) a[r] += (r < i) ? tt[r] : 0.f;
        float mu = bfl[0], al = bfl[1];
#pragma unroll
        for (int c = 0; c < 16; c++) { mu = fmaf(a[c], wf[c], mu); al = fmaf(a[c], wf[16 + c], al); }
        out[((size_t)(b * Nn + n)) * Dd + i] = (xin - mu) * __expf(-al);
        atomicAdd(logdet + b * Nn + n, -al);
    }
}

extern "C" void kernel_launch(void* const* d_in, const int* in_sizes, int n_in,
                              void* d_out, int out_size, void* d_ws, size_t ws_size,
                              hipStream_t stream) {
    const float* X  = (const float*)d_in[0];
    const float* ip = (const float*)d_in[1];
    const float* Wq = (const float*)d_in[2];
    const float* bq = (const float*)d_in[3];
    const float* Wk = (const float*)d_in[4];
    const float* bk = (const float*)d_in[5];
    const float* Wv = (const float*)d_in[6];
    const float* bv = (const float*)d_in[7];
    const float* Wo = (const float*)d_in[8];
    const float* bo = (const float*)d_in[9];
    const float* Wf = (const float*)d_in[10];
    const float* bf = (const float*)d_in[11];
    float* out = (float*)d_out;

    gf_init<<<(Bb * Nn + 255) / 256, 256, 0, stream>>>(X, ip, out);

    hipError_t e = hipFuncSetAttribute((const void*)gf_fused,
                                       hipFuncAttributeMaxDynamicSharedMemorySize,
                                       LDS_TOTAL);
    if (e == hipSuccess) {
        gf_fused<<<dim3(NL, Bb, 2), 1024, LDS_TOTAL, stream>>>(
            X, Wq, bq, Wk, bk, Wv, bv, Wo, bo, Wf, bf, out);
    } else {
        gf_layer_fb<<<dim3(NL, Bb), 512, 0, stream>>>(
            X, Wq, bq, Wk, bk, Wv, bv, Wo, bo, Wf, bf, out);
    }
}

// Round 12
// 159.441 us; speedup vs baseline: 1.0778x; 1.0778x over previous
//
#include <hip/hip_runtime.h>
#include <math.h>

#define Bb 16
#define Nn 1024
#define Dd 16
#define NL 15

typedef __attribute__((ext_vector_type(8))) short short8;
typedef __attribute__((ext_vector_type(16))) float f32x16;
typedef __attribute__((ext_vector_type(4))) unsigned uint4v;

#if __has_builtin(__builtin_amdgcn_exp2f)
#define EXP2(x) __builtin_amdgcn_exp2f(x)
#else
#define EXP2(x) exp2f(x)
#endif

// LDS layout (dynamic, 68224 B -> 2 blocks/CU = 136448 <= 160K):
//   K    : [1024 keys][16 shorts]          offset 0      32768 B
//   V^T  : [16 d][VSTR=1044 shorts]        offset 32768  33408 B
//   ones : [1024 shorts] bf16(1.0)         offset 66176   2048 B
//   O    : 16 waves x [32 q][17 f32]       offset 0      34816 B (overlays K)
//   rs   : 16 waves x [32 f32]             offset 36864   2048 B (in dead V)
#define VSTR 1044
#define V_OFF 32768
#define ONES_OFF 66176
#define RS_OFF 36864
#define LDS_TOTAL 68224

__device__ __forceinline__ unsigned pack2bf(float a, float b) {
    unsigned ua = __float_as_uint(a) + 0x8000u;
    unsigned ub = __float_as_uint(b) + 0x8000u;
    return (ua >> 16) | (ub & 0xffff0000u);
}
__device__ __forceinline__ unsigned short bf1(float a) {
    return (unsigned short)((__float_as_uint(a) + 0x8000u) >> 16);
}

// exp2 both, truncate-pack to bf16 pair in ONE v_perm_b32
__device__ __forceinline__ unsigned expperm(float x, float y) {
    unsigned ex = __float_as_uint(EXP2(x));
    unsigned ey = __float_as_uint(EXP2(y));
#if __has_builtin(__builtin_amdgcn_perm)
    return __builtin_amdgcn_perm(ey, ex, 0x07060302);   // {ey.hi16, ex.hi16}
#else
    return (ex >> 16) | (ey & 0xffff0000u);
#endif
}

__device__ __forceinline__ void project(const float* __restrict__ xrow,
                                        const float* __restrict__ W,
                                        const float* __restrict__ bias,
                                        int i, float* __restrict__ q) {
#pragma unroll
    for (int r = 0; r < 16; r++) q[r] = 0.f;
    for (int c = 0; c < i; c++) {
        float xc = xrow[c];
#pragma unroll
        for (int r = 0; r < 16; r++) q[r] = fmaf(xc, W[r * 16 + c], q[r]);
    }
#pragma unroll
    for (int r = 0; r < 16; r++) q[r] = (r < i) ? (q[r] + bias[r]) : 0.f;
}

__device__ __forceinline__ void load_row16(const float* __restrict__ p, float* __restrict__ x) {
    const float4* xp = (const float4*)p;
    float4 a = xp[0], b = xp[1], c = xp[2], d = xp[3];
    x[0]=a.x; x[1]=a.y; x[2]=a.z; x[3]=a.w;
    x[4]=b.x; x[5]=b.y; x[6]=b.z; x[7]=b.w;
    x[8]=c.x; x[9]=c.y; x[10]=c.z; x[11]=c.w;
    x[12]=d.x; x[13]=d.y; x[14]=d.z; x[15]=d.w;
}

// two b64 LDS reads -> one B-frag (keys {base+4h+0..3, base+8+4h+0..3})
__device__ __forceinline__ short8 ldv(const unsigned short* __restrict__ p) {
    uint2 a = *(const uint2*)p;
    uint2 b = *(const uint2*)(p + 8);
    uint4v v = {a.x, a.y, b.x, b.y};
    return __builtin_bit_cast(short8, v);
}

// ---------------------------------------------------------------------------
// Layer 0: Z col 0 + logdet = -alpha0 (atomicAdd target for the layers)
// ---------------------------------------------------------------------------
__global__ void gf_init(const float* __restrict__ X, const float* __restrict__ ip,
                        float* __restrict__ out) {
    int idx = blockIdx.x * blockDim.x + threadIdx.x;
    if (idx >= Bb * Nn) return;
    float mu = ip[0], alpha = ip[1];
    float x0 = X[(size_t)idx * Dd];
    out[(size_t)idx * Dd] = (x0 - mu) * __expf(-alpha);
    out[(size_t)Bb * Nn * Dd + idx] = -alpha;
}

// ---------------------------------------------------------------------------
// Fused flash attention, single 32-query stream/wave, grid (NL, Bb, 2).
// Register-diet build: epilogue Q reconstructed from the live qf fragment
// (shfl from lane+32) instead of reloading X + 256-FMA projection; proj
// phase scopes xr to die before xq. Goal: fit the allocator's 64-reg
// (32 arch + 32 acc) target for 8 waves/SIMD WITHOUT scratch spills
// (R10/R11 spilled ~40MB; R11 post-mortem located spills in proj/epilogue).
// ---------------------------------------------------------------------------
__launch_bounds__(1024, 4)
__global__ void gf_fused(const float* __restrict__ X,
                         const float* __restrict__ Wq, const float* __restrict__ bq,
                         const float* __restrict__ Wk, const float* __restrict__ bk,
                         const float* __restrict__ Wv, const float* __restrict__ bv,
                         const float* __restrict__ Wo, const float* __restrict__ bo,
                         const float* __restrict__ Wf, const float* __restrict__ bf,
                         float* __restrict__ out) {
    extern __shared__ char smem[];
    const int l = blockIdx.x, b = blockIdx.y, z = blockIdx.z, i = l + 1;
    const int t = threadIdx.x;
    const int wid = t >> 6, lane = t & 63;
    const int q31 = lane & 31, h = lane >> 5;
    const int qbase = z * 512 + wid * 32;            // wave's 32 queries
    const float qscale = 1.4426950408889634f * rsqrtf((float)i);

    unsigned short* Ksh  = (unsigned short*)smem;
    unsigned short* Vsh  = (unsigned short*)(smem + V_OFF);
    unsigned short* Ones = (unsigned short*)(smem + ONES_OFF);

    const float* Xb  = X  + (size_t)b * Nn * Dd;
    const float* wq  = Wq + l * 256;  const float* bql = bq + l * 16;
    const float* wk  = Wk + l * 256;  const float* bkl = bk + l * 16;
    const float* wvp = Wv + l * 256;  const float* bvl = bv + l * 16;
    const float* wo  = Wo + l * 256;  const float* bol = bo + l * 16;
    const float* wf  = Wf + l * 32;   const float* bfl = bf + l * 2;

    // ---- proj phase: thread t stages K/V row t; Q for its wave's query ----
    unsigned qu[8];                  // Q row (qbase + q31), scaled, bf16 pairs
    {
        {   // K + V from row t (xr dies at end of this scope)
            float xr[16]; load_row16(Xb + (size_t)t * Dd, xr);
            float tmp[16];
            project(xr, wk, bkl, i, tmp);
            {
                unsigned u[8];
#pragma unroll
                for (int r = 0; r < 8; r++) u[r] = pack2bf(tmp[2*r], tmp[2*r+1]);
                uint4* kd = (uint4*)(Ksh + t * 16);
                kd[0] = make_uint4(u[0], u[1], u[2], u[3]);
                kd[1] = make_uint4(u[4], u[5], u[6], u[7]);
            }
            project(xr, wvp, bvl, i, tmp);
#pragma unroll
            for (int d = 0; d < 16; d++) Vsh[d * VSTR + t] = bf1(tmp[d]);
        }
        Ones[t] = 0x3F80;            // bf16(1.0)

        {   // Q from row qbase+q31 (fresh xr scope)
            float xq[16]; load_row16(Xb + (size_t)(qbase + q31) * Dd, xq);
            float tmp[16];
            project(xq, wq, bql, i, tmp);
#pragma unroll
            for (int r = 0; r < 8; r++)
                qu[r] = pack2bf(tmp[2*r] * qscale, tmp[2*r+1] * qscale);
        }
    }
    __syncthreads();

    // ---- Q B-frag via same-wave shuffles: B[col=q31][k=8h+j] ----
    unsigned qfd[4];                 // keep as dwords (also epilogue source)
#pragma unroll
    for (int j = 0; j < 4; j++) {
        unsigned lo = __shfl(qu[j], q31);
        unsigned hi = __shfl(qu[4 + j], q31);
        qfd[j] = h ? hi : lo;
    }
    short8 qf;
    {
        uint4v v0 = {qfd[0], qfd[1], qfd[2], qfd[3]};
        qf = __builtin_bit_cast(short8, v0);
    }

    // ---------------- attention loop (32 keys/iter) ----------------
    f32x16 zf16 = {};
    f32x16 D0 = {};

    const unsigned short* Kp = Ksh + (size_t)q31 * 16 + h * 8;   // A: K[key][8h+j]
    const unsigned short* Vp = ((q31 < 16) ? (Vsh + (size_t)q31 * VSTR) : Ones) + 4 * h;

    short8 kf = *(const short8*)Kp;

    for (int kb = 0; kb < Nn; kb += 32) {
        const int kn = (kb + 32) & (Nn - 1);
        short8 vc0 = ldv(Vp + kb);
        short8 vc1 = ldv(Vp + kb + 16);

        f32x16 s0 = __builtin_amdgcn_mfma_f32_32x32x16_bf16(kf, qf, zf16, 0, 0, 0);
        kf = *(const short8*)(Kp + (size_t)kn * 16);   // prefetch next K frag

        {   // sub-chunk 0: S regs 0..7 (keys kb+{4h+0..3, 8+4h+0..3})
            uint4v a0 = {expperm(s0[0], s0[1]), expperm(s0[2], s0[3]),
                         expperm(s0[4], s0[5]), expperm(s0[6], s0[7])};
            D0 = __builtin_amdgcn_mfma_f32_32x32x16_bf16(
                     __builtin_bit_cast(short8, a0), vc0, D0, 0, 0, 0);
        }
        {   // sub-chunk 1: S regs 8..15 (keys kb+16+{4h+0..3, 8+4h+0..3})
            uint4v a1 = {expperm(s0[8], s0[9]),  expperm(s0[10], s0[11]),
                         expperm(s0[12], s0[13]), expperm(s0[14], s0[15])};
            D0 = __builtin_amdgcn_mfma_f32_32x32x16_bf16(
                     __builtin_bit_cast(short8, a1), vc1, D0, 0, 0, 0);
        }
    }

    // ---- gather other half of this query's Q (lane L+32 holds elems 8..15).
    // Executed by ALL lanes (before divergence) so source lanes are active.
    unsigned qhi[4];
#pragma unroll
    for (int j = 0; j < 4; j++) qhi[j] = __shfl(qfd[j], q31 + 32);
    unsigned qlo[4];
#pragma unroll
    for (int j = 0; j < 4; j++) qlo[j] = __shfl(qfd[j], q31);

    __syncthreads();   // all waves done with K/V before O overlays them

    // ---- stage O (C-layout -> [q_local][d] stride 17) + rs; wave-local ----
    float* Ow = (float*)smem + wid * (32 * 17);
    if (q31 < 16) {
#pragma unroll
        for (int r = 0; r < 16; r++) {
            int m = (r & 3) + 8 * (r >> 2) + 4 * h;   // query within wave's 32
            Ow[m * 17 + q31] = D0[r];
        }
    }
    float* Rw = (float*)(smem + RS_OFF) + wid * 32;
    if (q31 == 16) {                 // col 16 of D = sum of P = rs
#pragma unroll
        for (int r = 0; r < 16; r++) {
            int m = (r & 3) + 8 * (r >> 2) + 4 * h;
            Rw[m] = D0[r];
        }
    }
    // same-wave LDS ops are in program order; epilogue reads own-wave data.

    // ---- epilogue: lanes 0..31 handle query qbase+lane ----
    if (lane < 32) {
        const int n = qbase + lane;
        const float invq = 0.6931471805599453f * sqrtf((float)i);  // 1/qscale

        // reconstruct q (bf16-rounded, unscaled) from qlo/qhi
        float a[16];
#pragma unroll
        for (int j = 0; j < 4; j++) {
            a[2*j]      = __uint_as_float(qlo[j] << 16) * invq;
            a[2*j + 1]  = __uint_as_float(qlo[j] & 0xffff0000u) * invq;
            a[8 + 2*j]  = __uint_as_float(qhi[j] << 16) * invq;
            a[9 + 2*j]  = __uint_as_float(qhi[j] & 0xffff0000u) * invq;
        }

        const float* orow = (const float*)smem + wid * (32 * 17) + lane * 17;
        const float  inv  = 1.f / Rw[lane];
#pragma unroll
        for (int c = 0; c < 16; c++) a[c] += orow[c] * inv;

        float tt[16];
#pragma unroll
        for (int r = 0; r < 16; r++) {
            float acc = bol[r];
#pragma unroll
            for (int c = 0; c < 16; c++) acc = fmaf(a[c], wo[r * 16 + c], acc);
            tt[r] = fmaxf(acc, 0.f);
        }
#pragma unroll
        for (int r = 0; r < 16; r++) a[r] += (r < i) ? tt[r] : 0.f;

        float mu = bfl[0], al = bfl[1];
#pragma unroll
        for (int c = 0; c < 16; c++) {
            mu = fmaf(a[c], wf[c], mu);
            al = fmaf(a[c], wf[16 + c], al);
        }
        const float xi = Xb[(size_t)n * Dd + i];
        out[((size_t)(b * Nn + n)) * Dd + i] = (xi - mu) * __expf(-al);
        atomicAdd(out + (size_t)Bb * Nn * Dd + b * Nn + n, -al);
    }
}

// ---------------------------------------------------------------------------
// Fallback path (R1): fp32 kernel, if big dynamic LDS unavailable
// ---------------------------------------------------------------------------
__launch_bounds__(512, 2)
__global__ void gf_layer_fb(const float* __restrict__ X,
                            const float* __restrict__ Wq, const float* __restrict__ bq,
                            const float* __restrict__ Wk, const float* __restrict__ bk,
                            const float* __restrict__ Wv, const float* __restrict__ bv,
                            const float* __restrict__ Wo, const float* __restrict__ bo,
                            const float* __restrict__ Wf, const float* __restrict__ bf,
                            float* __restrict__ out) {
    const int l = blockIdx.x, b = blockIdx.y, i = l + 1, t = threadIdx.x;
    const float rscale = rsqrtf((float)i);
    __shared__ float Ksh[512 * 16];
    __shared__ float Vsh[512 * 16];
    const float* Xb = X + (size_t)b * Nn * Dd;
    const float* wq = Wq + l * 256; const float* wk = Wk + l * 256;
    const float* wv = Wv + l * 256; const float* wo = Wo + l * 256;
    const float* wf = Wf + l * 32;
    const float* bql = bq + l * 16; const float* bkl = bk + l * 16;
    const float* bvl = bv + l * 16; const float* bol = bo + l * 16;
    const float* bfl = bf + l * 2;
    const int n0 = t, n1 = t + 512;
    float q0[16], q1[16], xi0, xi1;
    {
        float xr[16];
        load_row16(Xb + (size_t)n0 * Dd, xr); xi0 = xr[i]; project(xr, wq, bql, i, q0);
        load_row16(Xb + (size_t)n1 * Dd, xr); xi1 = xr[i]; project(xr, wq, bql, i, q1);
    }
    float o0[16], o1[16];
#pragma unroll
    for (int c = 0; c < 16; c++) { o0[c] = 0.f; o1[c] = 0.f; }
    float ls0 = 0.f, ls1 = 0.f;
    for (int ch = 0; ch < 2; ch++) {
        float kr[16], vr[16];
        {
            float kx[16];
            load_row16(Xb + (size_t)(ch * 512 + t) * Dd, kx);
            project(kx, wk, bkl, i, kr);
            project(kx, wv, bvl, i, vr);
        }
        __syncthreads();
#pragma unroll
        for (int j = 0; j < 4; j++) {
            ((float4*)&Ksh[t * 16])[j] = ((float4*)kr)[j];
            ((float4*)&Vsh[t * 16])[j] = ((float4*)vr)[j];
        }
        __syncthreads();
        for (int k = 0; k < 512; k++) {
            float kk[16], vv[16];
#pragma unroll
            for (int j = 0; j < 4; j++) ((float4*)kk)[j] = ((const float4*)&Ksh[k * 16])[j];
            float s0 = 0.f, s1 = 0.f;
#pragma unroll
            for (int c = 0; c < 16; c++) { s0 = fmaf(q0[c], kk[c], s0); s1 = fmaf(q1[c], kk[c], s1); }
            float p0 = __expf(s0 * rscale), p1 = __expf(s1 * rscale);
            ls0 += p0; ls1 += p1;
#pragma unroll
            for (int j = 0; j < 4; j++) ((float4*)vv)[j] = ((const float4*)&Vsh[k * 16])[j];
#pragma unroll
            for (int c = 0; c < 16; c++) { o0[c] = fmaf(p0, vv[c], o0[c]); o1[c] = fmaf(p1, vv[c], o1[c]); }
        }
        __syncthreads();
    }
    float* logdet = out + (size_t)Bb * Nn * Dd;
#pragma unroll
    for (int rowsel = 0; rowsel < 2; rowsel++) {
        const float* qr = rowsel ? q1 : q0; const float* orr = rowsel ? o1 : o0;
        float lsum = rowsel ? ls1 : ls0; float xin = rowsel ? xi1 : xi0;
        int n = rowsel ? n1 : n0;
        float a[16]; float inv = 1.f / lsum;
#pragma unroll
        for (int c = 0; c < 16; c++) a[c] = qr[c] + orr[c] * inv;
        float tt[16];
#pragma unroll
        for (int r = 0; r < 16; r++) {
            float acc = bol[r];
#pragma unroll
            for (int c = 0; c < 16; c++) acc = fmaf(a[c], wo[r * 16 + c], acc);
            tt[r] = fmaxf(acc, 0.f);
        }
#pragma unroll
        for (int r = 0; r < 16; r++) a[r] += (r < i) ? tt[r] : 0.f;
        float mu = bfl[0], al = bfl[1];
#pragma unroll
        for (int c = 0; c < 16; c++) { mu = fmaf(a[c], wf[c], mu); al = fmaf(a[c], wf[16 + c], al); }
        out[((size_t)(b * Nn + n)) * Dd + i] = (xin - mu) * __expf(-al);
        atomicAdd(logdet + b * Nn + n, -al);
    }
}

extern "C" void kernel_launch(void* const* d_in, const int* in_sizes, int n_in,
                              void* d_out, int out_size, void* d_ws, size_t ws_size,
                              hipStream_t stream) {
    const float* X  = (const float*)d_in[0];
    const float* ip = (const float*)d_in[1];
    const float* Wq = (const float*)d_in[2];
    const float* bq = (const float*)d_in[3];
    const float* Wk = (const float*)d_in[4];
    const float* bk = (const float*)d_in[5];
    const float* Wv = (const float*)d_in[6];
    const float* bv = (const float*)d_in[7];
    const float* Wo = (const float*)d_in[8];
    const float* bo = (const float*)d_in[9];
    const float* Wf = (const float*)d_in[10];
    const float* bf = (const float*)d_in[11];
    float* out = (float*)d_out;

    gf_init<<<(Bb * Nn + 255) / 256, 256, 0, stream>>>(X, ip, out);

    hipError_t e = hipFuncSetAttribute((const void*)gf_fused,
                                       hipFuncAttributeMaxDynamicSharedMemorySize,
                                       LDS_TOTAL);
    if (e == hipSuccess) {
        gf_fused<<<dim3(NL, Bb, 2), 1024, LDS_TOTAL, stream>>>(
            X, Wq, bq, Wk, bk, Wv, bv, Wo, bo, Wf, bf, out);
    } else {
        gf_layer_fb<<<dim3(NL, Bb), 512, 0, stream>>>(
            X, Wq, bq, Wk, bk, Wv, bv, Wo, bo, Wf, bf, out);
    }
}

// Round 13
// 133.376 us; speedup vs baseline: 1.2885x; 1.1954x over previous
//
#include <hip/hip_runtime.h>
#include <math.h>

#define Bb 16
#define Nn 1024
#define Dd 16
#define NL 15

typedef __attribute__((ext_vector_type(8))) short short8;
typedef __attribute__((ext_vector_type(16))) float f32x16;
typedef __attribute__((ext_vector_type(4))) unsigned uint4v;

#if __has_builtin(__builtin_amdgcn_exp2f)
#define EXP2(x) __builtin_amdgcn_exp2f(x)
#else
#define EXP2(x) exp2f(x)
#endif

// LDS layout (dynamic, 73728 B, 1 block/CU, 16 waves):
//   K    : [1024 keys][16 shorts]          offset 0      32768 B
//   V^T  : [16 d][VSTR=1040 shorts]        offset 32768  33280 B (2080-B rows:
//          16B-aligned; b128 V-frag reads are 4-phase bank-balanced)
//          V keys PRE-PERMUTED per 16-block (vperm) so one b128 = one B-frag
//   ones : [1024 shorts] bf16(1.0)         offset 66048   2048 B (loop-only;
//          overlaid by O after the barrier)
//   O    : 16 waves x [64 q][17 f32]       offset 0      69632 B (overlays
//          K+V+ones after the loop barrier)
//   rs   : 16 waves x [64 f32]             offset 69632   4096 B
#define VSTR 1040
#define V_OFF 32768
#define ONES_OFF 66048
#define RS_OFF 69632
#define LDS_TOTAL 73728

// round-half-up fp32->bf16 (proj staging)
__device__ __forceinline__ unsigned pack2bf(float a, float b) {
    unsigned ua = __float_as_uint(a) + 0x8000u;
    unsigned ub = __float_as_uint(b) + 0x8000u;
    return (ua >> 16) | (ub & 0xffff0000u);
}
__device__ __forceinline__ unsigned short bf1(float a) {
    return (unsigned short)((__float_as_uint(a) + 0x8000u) >> 16);
}

// exp2 both, truncate-pack to bf16 pair in ONE v_perm_b32
__device__ __forceinline__ unsigned expperm(float x, float y) {
    unsigned ex = __float_as_uint(EXP2(x));
    unsigned ey = __float_as_uint(EXP2(y));
#if __has_builtin(__builtin_amdgcn_perm)
    return __builtin_amdgcn_perm(ey, ex, 0x07060302);   // {ey.hi16, ex.hi16}
#else
    return (ex >> 16) | (ey & 0xffff0000u);
#endif
}

// key permutation within a 16-block so a b128 at short-offset 8h yields keys
// {4h+0..3, 8+4h+0..3} (the 32x32x16 A-frag key order of the C->A identity)
__device__ __forceinline__ int vperm(int m) {
    return (m & 3) + ((m & 8) >> 1) + ((m & 4) << 1);
}

__device__ __forceinline__ void project(const float* __restrict__ xrow,
                                        const float* __restrict__ W,
                                        const float* __restrict__ bias,
                                        int i, float* __restrict__ q) {
#pragma unroll
    for (int r = 0; r < 16; r++) q[r] = 0.f;
    for (int c = 0; c < i; c++) {
        float xc = xrow[c];
#pragma unroll
        for (int r = 0; r < 16; r++) q[r] = fmaf(xc, W[r * 16 + c], q[r]);
    }
#pragma unroll
    for (int r = 0; r < 16; r++) q[r] = (r < i) ? (q[r] + bias[r]) : 0.f;
}

__device__ __forceinline__ void load_row16(const float* __restrict__ p, float* __restrict__ x) {
    const float4* xp = (const float4*)p;
    float4 a = xp[0], b = xp[1], c = xp[2], d = xp[3];
    x[0]=a.x; x[1]=a.y; x[2]=a.z; x[3]=a.w;
    x[4]=b.x; x[5]=b.y; x[6]=b.z; x[7]=b.w;
    x[8]=c.x; x[9]=c.y; x[10]=c.z; x[11]=c.w;
    x[12]=d.x; x[13]=d.y; x[14]=d.z; x[15]=d.w;
}

// ---------------------------------------------------------------------------
// Layer 0: Z col 0 + logdet = -alpha0 (atomicAdd target for the layers)
// ---------------------------------------------------------------------------
__global__ void gf_init(const float* __restrict__ X, const float* __restrict__ ip,
                        float* __restrict__ out) {
    int idx = blockIdx.x * blockDim.x + threadIdx.x;
    if (idx >= Bb * Nn) return;
    float mu = ip[0], alpha = ip[1];
    float x0 = X[(size_t)idx * Dd];
    out[(size_t)idx * Dd] = (x0 - mu) * __expf(-alpha);
    out[(size_t)Bb * Nn * Dd + idx] = -alpha;
}

// ---------------------------------------------------------------------------
// Fused: proj -> barrier -> per-wave flash attn (all 32x32x16 MFMA, dual
// 32-query streams/wave, 64 q/wave) -> epilogue. R9 structure (best: 70.4us)
// + single-b128 V frags (pre-permuted, prefetched) + qu-reuse epilogue.
// grid (NL, Bb), 1024 threads. rs via ones-column; P pack via v_perm trunc.
// ---------------------------------------------------------------------------
__launch_bounds__(1024, 4)
__global__ void gf_fused(const float* __restrict__ X,
                         const float* __restrict__ Wq, const float* __restrict__ bq,
                         const float* __restrict__ Wk, const float* __restrict__ bk,
                         const float* __restrict__ Wv, const float* __restrict__ bv,
                         const float* __restrict__ Wo, const float* __restrict__ bo,
                         const float* __restrict__ Wf, const float* __restrict__ bf,
                         float* __restrict__ out) {
    extern __shared__ char smem[];
    const int l = blockIdx.x, b = blockIdx.y, i = l + 1;
    const int t = threadIdx.x;
    const int wid = t >> 6, lane = t & 63;
    const int q31 = lane & 31, h = lane >> 5;
    const float qscale = 1.4426950408889634f * rsqrtf((float)i);

    unsigned short* Ksh  = (unsigned short*)smem;
    unsigned short* Vsh  = (unsigned short*)(smem + V_OFF);
    unsigned short* Ones = (unsigned short*)(smem + ONES_OFF);

    const float* Xb  = X  + (size_t)b * Nn * Dd;
    const float* wq  = Wq + l * 256;  const float* bql = bq + l * 16;
    const float* wk  = Wk + l * 256;  const float* bkl = bk + l * 16;
    const float* wvp = Wv + l * 256;  const float* bvl = bv + l * 16;
    const float* wo  = Wo + l * 256;  const float* bol = bo + l * 16;
    const float* wf  = Wf + l * 32;   const float* bfl = bf + l * 2;

    // ---------------- proj phase: thread t = row n = t ----------------
    unsigned qu[8];                       // Q row t, scaled, bf16 pairs (live
                                          // through loop; reused in epilogue)
    {
        float xr[16]; load_row16(Xb + (size_t)t * Dd, xr);
        float tmp[16];

        project(xr, wk, bkl, i, tmp);
        {
            unsigned u[8];
#pragma unroll
            for (int r = 0; r < 8; r++) u[r] = pack2bf(tmp[2*r], tmp[2*r+1]);
            uint4* kd = (uint4*)(Ksh + t * 16);
            kd[0] = make_uint4(u[0], u[1], u[2], u[3]);
            kd[1] = make_uint4(u[4], u[5], u[6], u[7]);
        }

        project(xr, wvp, bvl, i, tmp);
        {
            unsigned short* vcol = Vsh + (t & ~15) + vperm(t & 15);
#pragma unroll
            for (int d = 0; d < 16; d++) vcol[d * VSTR] = bf1(tmp[d]);
        }

        Ones[t] = 0x3F80;                 // bf16(1.0)

        project(xr, wq, bql, i, tmp);
#pragma unroll
        for (int r = 0; r < 8; r++) qu[r] = pack2bf(tmp[2*r] * qscale, tmp[2*r+1] * qscale);
    }
    __syncthreads();

    // ---- Q B-frags via same-wave shuffles (wave wid owns rows wid*64..+63) --
    short8 qf0, qf1;
    {
        unsigned d0[4], d1[4];
#pragma unroll
        for (int j = 0; j < 4; j++) {
            unsigned lo = __shfl(qu[j], q31);
            unsigned hi = __shfl(qu[4 + j], q31);
            d0[j] = h ? hi : lo;
            lo = __shfl(qu[j], 32 + q31);
            hi = __shfl(qu[4 + j], 32 + q31);
            d1[j] = h ? hi : lo;
        }
        uint4v v0 = {d0[0], d0[1], d0[2], d0[3]};
        uint4v v1 = {d1[0], d1[1], d1[2], d1[3]};
        qf0 = __builtin_bit_cast(short8, v0);
        qf1 = __builtin_bit_cast(short8, v1);
    }

    // ---------------- attention loop ----------------
    f32x16 zf16 = {};
    f32x16 D0 = {}, D1 = {};

    const unsigned short* Kp = Ksh + (size_t)q31 * 16 + h * 8;   // A: K[key][8h+j]
    // lanes q31<16: permuted V^T row d=q31; lanes q31>=16: ones (rs col 16).
    // 8h inside: one b128 = one B-frag.
    const unsigned short* Vp = ((q31 < 16) ? (Vsh + (size_t)q31 * VSTR) : Ones) + 8 * h;

    short8 kf  = *(const short8*)Kp;
    short8 vc0 = *(const short8*)(Vp);
    short8 vc1 = *(const short8*)(Vp + 16);

    for (int kb = 0; kb < Nn; kb += 32) {
        const int kn = (kb + 32) & (Nn - 1);
        short8 kfn = *(const short8*)(Kp + (size_t)kn * 16);
        short8 vn0 = *(const short8*)(Vp + kn);
        short8 vn1 = *(const short8*)(Vp + kn + 16);

        f32x16 s0 = __builtin_amdgcn_mfma_f32_32x32x16_bf16(kf, qf0, zf16, 0, 0, 0);
        f32x16 s1 = __builtin_amdgcn_mfma_f32_32x32x16_bf16(kf, qf1, zf16, 0, 0, 0);
        kf = kfn;

        // sub-chunk 0: S regs 0..7 (keys kb+{4h+0..3, 8+4h+0..3})
        {
            uint4v a0 = {expperm(s0[0], s0[1]), expperm(s0[2], s0[3]),
                         expperm(s0[4], s0[5]), expperm(s0[6], s0[7])};
            D0 = __builtin_amdgcn_mfma_f32_32x32x16_bf16(
                     __builtin_bit_cast(short8, a0), vc0, D0, 0, 0, 0);
            uint4v a1 = {expperm(s1[0], s1[1]), expperm(s1[2], s1[3]),
                         expperm(s1[4], s1[5]), expperm(s1[6], s1[7])};
            D1 = __builtin_amdgcn_mfma_f32_32x32x16_bf16(
                     __builtin_bit_cast(short8, a1), vc0, D1, 0, 0, 0);
        }
        // sub-chunk 1: S regs 8..15 (keys kb+16+{4h+0..3, 8+4h+0..3})
        {
            uint4v a0 = {expperm(s0[8], s0[9]),  expperm(s0[10], s0[11]),
                         expperm(s0[12], s0[13]), expperm(s0[14], s0[15])};
            D0 = __builtin_amdgcn_mfma_f32_32x32x16_bf16(
                     __builtin_bit_cast(short8, a0), vc1, D0, 0, 0, 0);
            uint4v a1 = {expperm(s1[8], s1[9]),  expperm(s1[10], s1[11]),
                         expperm(s1[12], s1[13]), expperm(s1[14], s1[15])};
            D1 = __builtin_amdgcn_mfma_f32_32x32x16_bf16(
                     __builtin_bit_cast(short8, a1), vc1, D1, 0, 0, 0);
        }
        vc0 = vn0; vc1 = vn1;
    }

    __syncthreads();   // all waves done with K/V/ones before O overlays them

    // ---- stage O (C-layout -> [q_local][d] stride 17) + rs; wave-local ----
    float* Ow = (float*)smem + wid * (64 * 17);
    if (q31 < 16) {
#pragma unroll
        for (int r = 0; r < 16; r++) {
            int m = (r & 3) + 8 * (r >> 2) + 4 * h;
            Ow[m * 17 + q31]        = D0[r];
            Ow[(m + 32) * 17 + q31] = D1[r];
        }
    }
    float* Rw = (float*)(smem + RS_OFF) + wid * 64;
    if (q31 == 16) {                      // col 16 of D = sum of P = rs
#pragma unroll
        for (int r = 0; r < 16; r++) {
            int m = (r & 3) + 8 * (r >> 2) + 4 * h;
            Rw[m]      = D0[r];
            Rw[32 + m] = D1[r];
        }
    }
    // same-wave LDS ops are in program order; epilogue reads own-wave data.

    // ---------------- epilogue (thread t = query n = t) ----------------
    {
        const float invq = 0.6931471805599453f * sqrtf((float)i);  // 1/qscale

        // reconstruct q from own qu (bf16-rounded, exactly what the MFMA saw)
        float a[16];
#pragma unroll
        for (int r = 0; r < 8; r++) {
            a[2*r]     = __uint_as_float(qu[r] << 16) * invq;
            a[2*r + 1] = __uint_as_float(qu[r] & 0xffff0000u) * invq;
        }

        const float* orow = (const float*)smem + wid * (64 * 17) + lane * 17;
        const float  inv  = 1.f / Rw[lane];
#pragma unroll
        for (int c = 0; c < 16; c++) a[c] += orow[c] * inv;

        float tt[16];
#pragma unroll
        for (int r = 0; r < 16; r++) {
            float acc = bol[r];
#pragma unroll
            for (int c = 0; c < 16; c++) acc = fmaf(a[c], wo[r * 16 + c], acc);
            tt[r] = fmaxf(acc, 0.f);
        }
#pragma unroll
        for (int r = 0; r < 16; r++) a[r] += (r < i) ? tt[r] : 0.f;

        float mu = bfl[0], al = bfl[1];
#pragma unroll
        for (int c = 0; c < 16; c++) {
            mu = fmaf(a[c], wf[c], mu);
            al = fmaf(a[c], wf[16 + c], al);
        }
        const float xi = Xb[(size_t)t * Dd + i];
        out[((size_t)(b * Nn + t)) * Dd + i] = (xi - mu) * __expf(-al);
        atomicAdd(out + (size_t)Bb * Nn * Dd + b * Nn + t, -al);
    }
}

// ---------------------------------------------------------------------------
// Fallback path (R1): fp32 kernel, if big dynamic LDS unavailable
// ---------------------------------------------------------------------------
__launch_bounds__(512, 2)
__global__ void gf_layer_fb(const float* __restrict__ X,
                            const float* __restrict__ Wq, const float* __restrict__ bq,
                            const float* __restrict__ Wk, const float* __restrict__ bk,
                            const float* __restrict__ Wv, const float* __restrict__ bv,
                            const float* __restrict__ Wo, const float* __restrict__ bo,
                            const float* __restrict__ Wf, const float* __restrict__ bf,
                            float* __restrict__ out) {
    const int l = blockIdx.x, b = blockIdx.y, i = l + 1, t = threadIdx.x;
    const float rscale = rsqrtf((float)i);
    __shared__ float Ksh[512 * 16];
    __shared__ float Vsh[512 * 16];
    const float* Xb = X + (size_t)b * Nn * Dd;
    const float* wq = Wq + l * 256; const float* wk = Wk + l * 256;
    const float* wv = Wv + l * 256; const float* wo = Wo + l * 256;
    const float* wf = Wf + l * 32;
    const float* bql = bq + l * 16; const float* bkl = bk + l * 16;
    const float* bvl = bv + l * 16; const float* bol = bo + l * 16;
    const float* bfl = bf + l * 2;
    const int n0 = t, n1 = t + 512;
    float q0[16], q1[16], xi0, xi1;
    {
        float xr[16];
        load_row16(Xb + (size_t)n0 * Dd, xr); xi0 = xr[i]; project(xr, wq, bql, i, q0);
        load_row16(Xb + (size_t)n1 * Dd, xr); xi1 = xr[i]; project(xr, wq, bql, i, q1);
    }
    float o0[16], o1[16];
#pragma unroll
    for (int c = 0; c < 16; c++) { o0[c] = 0.f; o1[c] = 0.f; }
    float ls0 = 0.f, ls1 = 0.f;
    for (int ch = 0; ch < 2; ch++) {
        float kr[16], vr[16];
        {
            float kx[16];
            load_row16(Xb + (size_t)(ch * 512 + t) * Dd, kx);
            project(kx, wk, bkl, i, kr);
            project(kx, wv, bvl, i, vr);
        }
        __syncthreads();
#pragma unroll
        for (int j = 0; j < 4; j++) {
            ((float4*)&Ksh[t * 16])[j] = ((float4*)kr)[j];
            ((float4*)&Vsh[t * 16])[j] = ((float4*)vr)[j];
        }
        __syncthreads();
        for (int k = 0; k < 512; k++) {
            float kk[16], vv[16];
#pragma unroll
            for (int j = 0; j < 4; j++) ((float4*)kk)[j] = ((const float4*)&Ksh[k * 16])[j];
            float s0 = 0.f, s1 = 0.f;
#pragma unroll
            for (int c = 0; c < 16; c++) { s0 = fmaf(q0[c], kk[c], s0); s1 = fmaf(q1[c], kk[c], s1); }
            float p0 = __expf(s0 * rscale), p1 = __expf(s1 * rscale);
            ls0 += p0; ls1 += p1;
#pragma unroll
            for (int j = 0; j < 4; j++) ((float4*)vv)[j] = ((const float4*)&Vsh[k * 16])[j];
#pragma unroll
            for (int c = 0; c < 16; c++) { o0[c] = fmaf(p0, vv[c], o0[c]); o1[c] = fmaf(p1, vv[c], o1[c]); }
        }
        __syncthreads();
    }
    float* logdet = out + (size_t)Bb * Nn * Dd;
#pragma unroll
    for (int rowsel = 0; rowsel < 2; rowsel++) {
        const float* qr = rowsel ? q1 : q0; const float* orr = rowsel ? o1 : o0;
        float lsum = rowsel ? ls1 : ls0; float xin = rowsel ? xi1 : xi0;
        int n = rowsel ? n1 : n0;
        float a[16]; float inv = 1.f / lsum;
#pragma unroll
        for (int c = 0; c < 16; c++) a[c] = qr[c] + orr[c] * inv;
        float tt[16];
#pragma unroll
        for (int r = 0; r < 16; r++) {
            float acc = bol[r];
#pragma unroll
            for (int c = 0; c < 16; c++) acc = fmaf(a[c], wo[r * 16 + c], acc);
            tt[r] = fmaxf(acc, 0.f);
        }
#pragma unroll
        for (int r = 0; r < 16; r++) a[r] += (r < i) ? tt[r] : 0.f;
        float mu = bfl[0], al = bfl[1];
#pragma unroll
        for (int c = 0; c < 16; c++) { mu = fmaf(a[c], wf[c], mu); al = fmaf(a[c], wf[16 + c], al); }
        out[((size_t)(b * Nn + n)) * Dd + i] = (xin - mu) * __expf(-al);
        atomicAdd(logdet + b * Nn + n, -al);
    }
}

extern "C" void kernel_launch(void* const* d_in, const int* in_sizes, int n_in,
                              void* d_out, int out_size, void* d_ws, size_t ws_size,
                              hipStream_t stream) {
    const float* X  = (const float*)d_in[0];
    const float* ip = (const float*)d_in[1];
    const float* Wq = (const float*)d_in[2];
    const float* bq = (const float*)d_in[3];
    const float* Wk = (const float*)d_in[4];
    const float* bk = (const float*)d_in[5];
    const float* Wv = (const float*)d_in[6];
    const float* bv = (const float*)d_in[7];
    const float* Wo = (const float*)d_in[8];
    const float* bo = (const float*)d_in[9];
    const float* Wf = (const float*)d_in[10];
    const float* bf = (const float*)d_in[11];
    float* out = (float*)d_out;

    gf_init<<<(Bb * Nn + 255) / 256, 256, 0, stream>>>(X, ip, out);

    hipError_t e = hipFuncSetAttribute((const void*)gf_fused,
                                       hipFuncAttributeMaxDynamicSharedMemorySize,
                                       LDS_TOTAL);
    if (e == hipSuccess) {
        gf_fused<<<dim3(NL, Bb), 1024, LDS_TOTAL, stream>>>(
            X, Wq, bq, Wk, bk, Wv, bv, Wo, bo, Wf, bf, out);
    } else {
        gf_layer_fb<<<dim3(NL, Bb), 512, 0, stream>>>(
            X, Wq, bq, Wk, bk, Wv, bv, Wo, bo, Wf, bf, out);
    }
}